// Round 2
// baseline (250.231 us; speedup 1.0000x reference)
//
#include <hip/hip_runtime.h>
#include <hip/hip_bf16.h>

#define VOCABN 50000
#define BN 128
#define CN 5
#define HN 50
#define LN 32
#define DN 300
#define DP 320     // padded K
#define KNN 20

typedef __bf16 bf16x8 __attribute__((ext_vector_type(8)));
typedef float  f32x4  __attribute__((ext_vector_type(4)));

#if __has_builtin(__builtin_amdgcn_exp2f)
#define FEXP2 __builtin_amdgcn_exp2f
#else
#define FEXP2 exp2f
#endif
#if __has_builtin(__builtin_amdgcn_logf)
#define FLOG2 __builtin_amdgcn_logf
#else
#define FLOG2 log2f
#endif

#define LOG2E 1.4426950408889634f
#define LN2F  0.6931471805599453f

// ---------------- kernel 1: normalize vocab -> bf16 table [VOCAB][DP] ----------------
__global__ __launch_bounds__(256) void knorm_embed(const float* __restrict__ emb,
                                                   __hip_bfloat162* __restrict__ tab2) {
    const int v = blockIdx.x;
    const float* row = emb + (size_t)v * DN;
    const int t = threadIdx.x;

    float x0 = (t < DN) ? row[t] : 0.f;
    float x1 = (t + 256 < DN) ? row[t + 256] : 0.f;
    float ss = x0 * x0 + x1 * x1;
    #pragma unroll
    for (int off = 32; off; off >>= 1) ss += __shfl_xor(ss, off);
    __shared__ float red[4];
    if ((t & 63) == 0) red[t >> 6] = ss;
    __syncthreads();
    float tot = red[0] + red[1] + red[2] + red[3];
    float scale = 1.0f / fmaxf(sqrtf(tot), 1e-8f);

    if (t < DP / 2) {                 // 160 bf16 pairs per row
        int e = t * 2;
        float a = (e < DN) ? row[e] * scale : 0.f;
        float b = (e + 1 < DN) ? row[e + 1] * scale : 0.f;
        __hip_bfloat162 p;
        p.x = __float2bfloat16(a);
        p.y = __float2bfloat16(b);
        tab2[(size_t)v * (DP / 2) + t] = p;
    }
}

// ---------------- kernel 2: fused sim(MFMA) + kernel pooling + score partial ----------------
// B-buf layout: [32 rows][640 B], 16B chunks XOR-swizzled within 8-chunk octets.
__device__ inline bf16x8 ldB(const ushort* buf, int row, int ks, int g4) {
    int c = ks * 4 + g4;                              // chunk 0..39
    int pos = (c & ~7) | ((c & 7) ^ (row & 7));
    return *(const bf16x8*)((const char*)buf + row * 640 + pos * 16);
}

__global__ __launch_bounds__(320) void knrm_fused(const int* __restrict__ cand,
                                                  const int* __restrict__ clik,
                                                  const ushort* __restrict__ tab,   // bf16 bits
                                                  const float* __restrict__ ltr_w,
                                                  float* __restrict__ score) {
    __shared__ __align__(16) ushort Bbuf[2][32 * 320];   // 40 KB, double-buffered
    __shared__ __align__(16) float  simbuf[160 * 36];    // 22.5 KB, stride 36 (16B aligned)
    __shared__ int   tokA[160];
    __shared__ int   tokB[160];
    __shared__ float red[5][5];

    const int t    = threadIdx.x;
    const int lane = t & 63;
    const int w    = t >> 6;          // wave 0..4
    const int bid  = blockIdx.x;
    const int b    = bid / 10;        // 10 h-chunks of 5
    const int hc   = bid % 10;

    if (t < 160) tokA[t] = cand[b * (CN * LN) + t];
    else         tokB[t - 160] = clik[b * (HN * LN) + hc * 160 + (t - 160)];
    __syncthreads();

    const int m15 = lane & 15;
    const int g4  = lane >> 4;
    const int rA0 = w * 32 + m15;

    // ---- A fragments in registers for the whole block (no A staging) ----
    bf16x8 afrag[2][10];
    {
        const char* pa0 = (const char*)tab + (size_t)tokA[rA0]      * (DP * 2) + g4 * 16;
        const char* pa1 = (const char*)tab + (size_t)tokA[rA0 + 16] * (DP * 2) + g4 * 16;
        #pragma unroll
        for (int ks = 0; ks < 10; ++ks) {
            afrag[0][ks] = *(const bf16x8*)(pa0 + ks * 64);
            afrag[1][ks] = *(const bf16x8*)(pa1 + ks * 64);
        }
    }

    // ---- staging geometry: 1280 chunks of 16B, 4 per thread ----
    const int srow0 = t / 40;                           // 0..7
    const int sc    = t % 40;                           // chunk within row
    const int spos  = (sc & ~7) | ((sc & 7) ^ (srow0 & 7));  // (row&7) invariant: it*8 ≡ 0 mod 8

    int4 breg[4];
    // stage B[0]
    #pragma unroll
    for (int it = 0; it < 4; ++it) {
        int row = srow0 + it * 8;
        breg[it] = *(const int4*)((const char*)tab + (size_t)tokB[row] * (DP * 2) + sc * 16);
    }
    #pragma unroll
    for (int it = 0; it < 4; ++it) {
        int row = srow0 + it * 8;
        *(int4*)((char*)&Bbuf[0][0] + row * 640 + spos * 16) = breg[it];
    }
    __syncthreads();

    // pooling constants: fixed kernel index per thread (320 = 16 x 20, exact)
    const int kq = t % 20;
    const int r0 = t / 20;            // 0..15
    const float sig = (kq == 19) ? 0.001f : 0.1f;
    const float ak  = sqrtf(LOG2E / (2.0f * sig * sig));
    const float bk  = -(0.1f * (float)kq - 0.9f) * ak;

    float accs[5] = {0.f, 0.f, 0.f, 0.f, 0.f};

    for (int h = 0; h < 5; ++h) {
        const ushort* bb = &Bbuf[h & 1][0];

        // T14: issue next-B global loads now; ds_write after the barrier
        if (h < 4) {
            #pragma unroll
            for (int it = 0; it < 4; ++it) {
                int row = srow0 + it * 8;
                breg[it] = *(const int4*)((const char*)tab +
                    (size_t)tokB[(h + 1) * 32 + row] * (DP * 2) + sc * 16);
            }
        }

        // ---- MFMA: A from regs, B from LDS ----
        f32x4 acc[2][2];
        #pragma unroll
        for (int mt = 0; mt < 2; ++mt)
            #pragma unroll
            for (int nt = 0; nt < 2; ++nt)
                acc[mt][nt] = (f32x4){0.f, 0.f, 0.f, 0.f};

        #pragma unroll
        for (int ks = 0; ks < 10; ++ks) {
            bf16x8 b0 = ldB(bb, m15,      ks, g4);
            bf16x8 b1 = ldB(bb, m15 + 16, ks, g4);
            acc[0][0] = __builtin_amdgcn_mfma_f32_16x16x32_bf16(afrag[0][ks], b0, acc[0][0], 0, 0, 0);
            acc[0][1] = __builtin_amdgcn_mfma_f32_16x16x32_bf16(afrag[0][ks], b1, acc[0][1], 0, 0, 0);
            acc[1][0] = __builtin_amdgcn_mfma_f32_16x16x32_bf16(afrag[1][ks], b0, acc[1][0], 0, 0, 0);
            acc[1][1] = __builtin_amdgcn_mfma_f32_16x16x32_bf16(afrag[1][ks], b1, acc[1][1], 0, 0, 0);
        }

        // sim tile -> LDS: C/D layout col=lane&15, row=(lane>>4)*4+reg  [m89-verified]
        #pragma unroll
        for (int mt = 0; mt < 2; ++mt)
            #pragma unroll
            for (int nt = 0; nt < 2; ++nt)
                #pragma unroll
                for (int r = 0; r < 4; ++r) {
                    int row = w * 32 + mt * 16 + (g4 << 2) + r;
                    int col = nt * 16 + m15;
                    simbuf[row * 36 + col] = acc[mt][nt][r];
                }
        __syncthreads();   // simbuf ready; all waves done reading Bbuf[h&1] (and [(h+1)&1] since h-1)

        // write next B into the other buffer (hidden under pooling)
        if (h < 4) {
            #pragma unroll
            for (int it = 0; it < 4; ++it) {
                int row = srow0 + it * 8;
                *(int4*)((char*)&Bbuf[(h + 1) & 1][0] + row * 640 + spos * 16) = breg[it];
            }
        }

        // ---- pooling: thread owns kernel kq, rows it*16+r0 ----
        const float wl = ltr_w[(hc * 5 + h) * KNN + kq] * LN2F;
        #pragma unroll
        for (int it = 0; it < 10; ++it) {
            const f32x4* srow = (const f32x4*)&simbuf[(it * 16 + r0) * 36];
            float p0 = 0.f, p1 = 0.f, p2 = 0.f, p3 = 0.f;
            #pragma unroll
            for (int jc = 0; jc < 8; ++jc) {
                f32x4 v = srow[jc];
                float d0 = fmaf(v[0], ak, bk);
                float d1 = fmaf(v[1], ak, bk);
                float d2 = fmaf(v[2], ak, bk);
                float d3 = fmaf(v[3], ak, bk);
                p0 += FEXP2(-(d0 * d0));
                p1 += FEXP2(-(d1 * d1));
                p2 += FEXP2(-(d2 * d2));
                p3 += FEXP2(-(d3 * d3));
            }
            float pooled = fmaxf((p0 + p1) + (p2 + p3), 1e-10f);
            accs[it >> 1] += FLOG2(pooled) * wl;        // it>>1 == row/32 == c (compile-time)
        }
        __syncthreads();   // simbuf free for next h; Bbuf[(h+1)&1] published
    }

    // block reduction of per-thread score partials (5 c-values)
    #pragma unroll
    for (int c = 0; c < 5; ++c) {
        float v = accs[c];
        #pragma unroll
        for (int off = 32; off; off >>= 1) v += __shfl_xor(v, off);
        accs[c] = v;
    }
    if (lane == 0)
        #pragma unroll
        for (int c = 0; c < 5; ++c) red[w][c] = accs[c];
    __syncthreads();
    if (t < 5) {
        float s = red[0][t] + red[1][t] + red[2][t] + red[3][t] + red[4][t];
        atomicAdd(&score[b * CN + t], s);
    }
}

// ---------------- kernel 3: log_softmax over C (ltr_b cancels) ----------------
__global__ __launch_bounds__(128) void knrm_final(const float* __restrict__ score,
                                                  float* __restrict__ out) {
    int b = threadIdx.x;
    if (b < BN) {
        float s[CN];
        float m = -1e30f;
        #pragma unroll
        for (int c = 0; c < CN; ++c) { s[c] = score[b * CN + c]; m = fmaxf(m, s[c]); }
        float sum = 0.f;
        #pragma unroll
        for (int c = 0; c < CN; ++c) sum += FEXP2((s[c] - m) * LOG2E);
        float lse = m + FLOG2(sum) * LN2F;
        #pragma unroll
        for (int c = 0; c < CN; ++c) out[b * CN + c] = s[c] - lse;
    }
}

extern "C" void kernel_launch(void* const* d_in, const int* in_sizes, int n_in,
                              void* d_out, int out_size, void* d_ws, size_t ws_size,
                              hipStream_t stream) {
    const int*   cand  = (const int*)d_in[0];   // [B,C,L]
    const int*   clik  = (const int*)d_in[1];   // [B,H,L]
    const float* emb   = (const float*)d_in[2]; // [VOCAB,D]
    const float* ltr_w = (const float*)d_in[3]; // [1,H*KN]
    // d_in[4] = ltr_b (cancels in log_softmax)
    float* out = (float*)d_out;

    __hip_bfloat162* tab2 = (__hip_bfloat162*)d_ws;
    ushort* tab = (ushort*)d_ws;                                    // bf16 bits view
    float* score = (float*)((char*)d_ws + (size_t)VOCABN * DP * 2); // 32 MB offset

    hipMemsetAsync(score, 0, BN * CN * sizeof(float), stream);
    knorm_embed<<<VOCABN, 256, 0, stream>>>(emb, tab2);
    knrm_fused<<<BN * 10, 320, 0, stream>>>(cand, clik, tab, ltr_w, score);
    knrm_final<<<1, 128, 0, stream>>>(score, out);
}

// Round 3
// 218.450 us; speedup vs baseline: 1.1455x; 1.1455x over previous
//
#include <hip/hip_runtime.h>
#include <hip/hip_bf16.h>

#define VOCABN 50000
#define BN 128
#define CN 5
#define HN 50
#define LN 32
#define DN 300
#define DP 320     // padded K
#define KNN 20

typedef __bf16    bf16x8 __attribute__((ext_vector_type(8)));
typedef float     f32x4  __attribute__((ext_vector_type(4)));
typedef _Float16  f16x8  __attribute__((ext_vector_type(8)));

#if __has_builtin(__builtin_amdgcn_exp2f)
#define FEXP2 __builtin_amdgcn_exp2f
#else
#define FEXP2 exp2f
#endif
#if __has_builtin(__builtin_amdgcn_logf)
#define FLOG2 __builtin_amdgcn_logf
#else
#define FLOG2 log2f
#endif

#define LOG2E 1.4426950408889634f
#define LN2F  0.6931471805599453f

// ---------------- kernel 1: normalize vocab -> bf16 table [VOCAB][DP] ----------------
__global__ __launch_bounds__(256) void knorm_embed(const float* __restrict__ emb,
                                                   __hip_bfloat162* __restrict__ tab2) {
    const int v = blockIdx.x;
    const float* row = emb + (size_t)v * DN;
    const int t = threadIdx.x;

    float x0 = (t < DN) ? row[t] : 0.f;
    float x1 = (t + 256 < DN) ? row[t + 256] : 0.f;
    float ss = x0 * x0 + x1 * x1;
    #pragma unroll
    for (int off = 32; off; off >>= 1) ss += __shfl_xor(ss, off);
    __shared__ float red[4];
    if ((t & 63) == 0) red[t >> 6] = ss;
    __syncthreads();
    float tot = red[0] + red[1] + red[2] + red[3];
    float scale = 1.0f / fmaxf(sqrtf(tot), 1e-8f);

    if (t < DP / 2) {                 // 160 bf16 pairs per row
        int e = t * 2;
        float a = (e < DN) ? row[e] * scale : 0.f;
        float b = (e + 1 < DN) ? row[e + 1] * scale : 0.f;
        __hip_bfloat162 p;
        p.x = __float2bfloat16(a);
        p.y = __float2bfloat16(b);
        tab2[(size_t)v * (DP / 2) + t] = p;
    }
}

// ---------------- kernel 2: fused sim(MFMA) + kernel pooling + score partial ----------------
// Slice buffers: [row][64 ushorts] = 128B rows; 16B chunks XOR-swizzled: LDS pos p
// holds global chunk p ^ (row&7)  (involution; R1-verified).
__device__ inline bf16x8 ldfrag(const ushort* buf, int row, int chunk) {
    int pos = chunk ^ (row & 7);
    return *(const bf16x8*)((const char*)buf + row * 128 + pos * 16);
}

__global__ __launch_bounds__(320, 4) void knrm_fused(const int* __restrict__ cand,
                                                     const int* __restrict__ clik,
                                                     const ushort* __restrict__ tab,   // bf16 bits
                                                     const float* __restrict__ ltr_w,
                                                     float* __restrict__ score) {
    __shared__ __align__(16) ushort   Abuf[160 * 64];   // 20 KB, one K=64 slice of A (160 rows)
    __shared__ __align__(16) ushort   Bbuf[160 * 64];   // 20 KB, one K=64 slice of B (5h x 32 rows)
    __shared__ __align__(16) _Float16 simbuf[160 * 32]; // 10 KB, stride 32 (64B rows)
    __shared__ int   tokA[160];
    __shared__ int   tokB[160];
    __shared__ float red[5][5];

    const int t    = threadIdx.x;
    const int lane = t & 63;
    const int w    = t >> 6;          // wave 0..4
    const int bid  = blockIdx.x;
    const int b    = bid / 10;        // 10 h-chunks of 5
    const int hc   = bid % 10;

    if (t < 160) tokA[t] = cand[b * (CN * LN) + t];
    else         tokB[t - 160] = clik[b * (HN * LN) + hc * 160 + (t - 160)];
    __syncthreads();

    const int m15 = lane & 15;
    const int g4  = lane >> 4;

    // all-h accumulators: acc[at][jg], at = A-row half (wave rows), jg = B row-group (j = jg*16 + ...)
    f32x4 acc[2][10];
    #pragma unroll
    for (int at = 0; at < 2; ++at)
        #pragma unroll
        for (int jg = 0; jg < 10; ++jg)
            acc[at][jg] = (f32x4){0.f, 0.f, 0.f, 0.f};

    // ---- GEMM: K-slice outer (5 slices of 64), A and B each staged exactly once ----
    for (int ss = 0; ss < 5; ++ss) {
        __syncthreads();                                  // slice buffers free
        {   // stage A: 1280 chunks of 16B, 4 per thread (then B, batched to cap VGPRs)
            int4 rg[4];
            #pragma unroll
            for (int it = 0; it < 4; ++it) {
                int cid = it * 320 + t, row = cid >> 3, c = cid & 7;
                rg[it] = *(const int4*)((const char*)tab +
                    (size_t)tokA[row] * (DP * 2) + ss * 128 + ((c ^ (row & 7)) << 4));
            }
            #pragma unroll
            for (int it = 0; it < 4; ++it) {
                int cid = it * 320 + t, row = cid >> 3, c = cid & 7;
                *(int4*)((char*)Abuf + row * 128 + c * 16) = rg[it];
            }
            #pragma unroll
            for (int it = 0; it < 4; ++it) {
                int cid = it * 320 + t, row = cid >> 3, c = cid & 7;
                rg[it] = *(const int4*)((const char*)tab +
                    (size_t)tokB[row] * (DP * 2) + ss * 128 + ((c ^ (row & 7)) << 4));
            }
            #pragma unroll
            for (int it = 0; it < 4; ++it) {
                int cid = it * 320 + t, row = cid >> 3, c = cid & 7;
                *(int4*)((char*)Bbuf + row * 128 + c * 16) = rg[it];
            }
        }
        __syncthreads();                                  // slice ready
        #pragma unroll
        for (int kc = 0; kc < 2; ++kc) {                  // two K=32 sub-steps
            bf16x8 af0 = ldfrag(Abuf, w * 32 + m15,      kc * 4 + g4);
            bf16x8 af1 = ldfrag(Abuf, w * 32 + 16 + m15, kc * 4 + g4);
            #pragma unroll
            for (int jg = 0; jg < 10; ++jg) {
                bf16x8 bf = ldfrag(Bbuf, jg * 16 + m15, kc * 4 + g4);
                acc[0][jg] = __builtin_amdgcn_mfma_f32_16x16x32_bf16(af0, bf, acc[0][jg], 0, 0, 0);
                acc[1][jg] = __builtin_amdgcn_mfma_f32_16x16x32_bf16(af1, bf, acc[1][jg], 0, 0, 0);
            }
        }
    }

    // ---- pooling: per h, dump sim tile (f16) then rolled kernel-pooling (R1-proven mapping) ----
    const int kq = t % 20;
    const int r0 = t / 20;            // 0..15
    const float sig = (kq == 19) ? 0.001f : 0.1f;
    const float ak  = sqrtf(LOG2E / (2.0f * sig * sig));
    const float bk  = -(0.1f * (float)kq - 0.9f) * ak;

    float accs[5] = {0.f, 0.f, 0.f, 0.f, 0.f};

    #pragma unroll
    for (int h = 0; h < 5; ++h) {     // unrolled: static acc indices (rule #20)
        __syncthreads();              // simbuf free (prev h's pooling done; first h: GEMM done)
        // sim write: C/D layout col=lane&15, row=(lane>>4)*4+reg [m89-verified]
        #pragma unroll
        for (int at = 0; at < 2; ++at)
            #pragma unroll
            for (int jgl = 0; jgl < 2; ++jgl)
                #pragma unroll
                for (int r = 0; r < 4; ++r) {
                    int i = w * 32 + at * 16 + g4 * 4 + r;   // A row (sim row)
                    int j = jgl * 16 + m15;                  // B col within h
                    simbuf[i * 32 + j] = (_Float16)acc[at][2 * h + jgl][r];
                }
        __syncthreads();              // simbuf ready

        const float wl = ltr_w[(hc * 5 + h) * KNN + kq] * LN2F;
        #pragma unroll
        for (int it = 0; it < 10; ++it) {
            const f16x8* srow = (const f16x8*)&simbuf[(it * 16 + r0) * 32];
            float p0 = 0.f, p1 = 0.f, p2 = 0.f, p3 = 0.f;
            #pragma unroll
            for (int jc = 0; jc < 4; ++jc) {
                f16x8 v = srow[jc];
                float d0 = fmaf((float)v[0], ak, bk);
                float d1 = fmaf((float)v[1], ak, bk);
                float d2 = fmaf((float)v[2], ak, bk);
                float d3 = fmaf((float)v[3], ak, bk);
                float d4 = fmaf((float)v[4], ak, bk);
                float d5 = fmaf((float)v[5], ak, bk);
                float d6 = fmaf((float)v[6], ak, bk);
                float d7 = fmaf((float)v[7], ak, bk);
                p0 += FEXP2(-(d0 * d0));
                p1 += FEXP2(-(d1 * d1));
                p2 += FEXP2(-(d2 * d2));
                p3 += FEXP2(-(d3 * d3));
                p0 += FEXP2(-(d4 * d4));
                p1 += FEXP2(-(d5 * d5));
                p2 += FEXP2(-(d6 * d6));
                p3 += FEXP2(-(d7 * d7));
            }
            float pooled = fmaxf((p0 + p1) + (p2 + p3), 1e-10f);
            accs[it >> 1] += FLOG2(pooled) * wl;          // it>>1 == row/32 == c (compile-time)
        }
    }

    // ---- block reduction of per-thread score partials (5 c-values) ----
    #pragma unroll
    for (int c = 0; c < 5; ++c) {
        float v = accs[c];
        #pragma unroll
        for (int off = 32; off; off >>= 1) v += __shfl_xor(v, off);
        accs[c] = v;
    }
    __syncthreads();                  // simbuf reads done before red[] reuse is irrelevant; keep ordering
    if (lane == 0)
        #pragma unroll
        for (int c = 0; c < 5; ++c) red[w][c] = accs[c];
    __syncthreads();
    if (t < 5) {
        float s = red[0][t] + red[1][t] + red[2][t] + red[3][t] + red[4][t];
        atomicAdd(&score[b * CN + t], s);
    }
}

// ---------------- kernel 3: log_softmax over C (ltr_b cancels) ----------------
__global__ __launch_bounds__(128) void knrm_final(const float* __restrict__ score,
                                                  float* __restrict__ out) {
    int b = threadIdx.x;
    if (b < BN) {
        float s[CN];
        float m = -1e30f;
        #pragma unroll
        for (int c = 0; c < CN; ++c) { s[c] = score[b * CN + c]; m = fmaxf(m, s[c]); }
        float sum = 0.f;
        #pragma unroll
        for (int c = 0; c < CN; ++c) sum += FEXP2((s[c] - m) * LOG2E);
        float lse = m + FLOG2(sum) * LN2F;
        #pragma unroll
        for (int c = 0; c < CN; ++c) out[b * CN + c] = s[c] - lse;
    }
}

extern "C" void kernel_launch(void* const* d_in, const int* in_sizes, int n_in,
                              void* d_out, int out_size, void* d_ws, size_t ws_size,
                              hipStream_t stream) {
    const int*   cand  = (const int*)d_in[0];   // [B,C,L]
    const int*   clik  = (const int*)d_in[1];   // [B,H,L]
    const float* emb   = (const float*)d_in[2]; // [VOCAB,D]
    const float* ltr_w = (const float*)d_in[3]; // [1,H*KN]
    // d_in[4] = ltr_b (cancels in log_softmax)
    float* out = (float*)d_out;

    __hip_bfloat162* tab2 = (__hip_bfloat162*)d_ws;
    ushort* tab = (ushort*)d_ws;                                    // bf16 bits view
    float* score = (float*)((char*)d_ws + (size_t)VOCABN * DP * 2); // 32 MB offset

    hipMemsetAsync(score, 0, BN * CN * sizeof(float), stream);
    knorm_embed<<<VOCABN, 256, 0, stream>>>(emb, tab2);
    knrm_fused<<<BN * 10, 320, 0, stream>>>(cand, clik, tab, ltr_w, score);
    knrm_final<<<1, 128, 0, stream>>>(score, out);
}

// Round 4
// 208.700 us; speedup vs baseline: 1.1990x; 1.0467x over previous
//
#include <hip/hip_runtime.h>
#include <hip/hip_bf16.h>

#define VOCABN 50000
#define BN 128
#define CN 5
#define HN 50
#define LN 32
#define DN 300
#define DP 320     // padded K
#define KNN 20

typedef __bf16    bf16x8 __attribute__((ext_vector_type(8)));
typedef float     f32x4  __attribute__((ext_vector_type(4)));
typedef _Float16  f16x8  __attribute__((ext_vector_type(8)));

#if __has_builtin(__builtin_amdgcn_exp2f)
#define FEXP2 __builtin_amdgcn_exp2f
#else
#define FEXP2 exp2f
#endif
#if __has_builtin(__builtin_amdgcn_logf)
#define FLOG2 __builtin_amdgcn_logf
#else
#define FLOG2 log2f
#endif

#define LOG2E 1.4426950408889634f
#define LN2F  0.6931471805599453f

// ---------------- kernel 1: normalize vocab -> bf16 table [VOCAB][DP] ----------------
__global__ __launch_bounds__(256) void knorm_embed(const float* __restrict__ emb,
                                                   __hip_bfloat162* __restrict__ tab2) {
    const int v = blockIdx.x;
    const float* row = emb + (size_t)v * DN;
    const int t = threadIdx.x;

    float x0 = (t < DN) ? row[t] : 0.f;
    float x1 = (t + 256 < DN) ? row[t + 256] : 0.f;
    float ss = x0 * x0 + x1 * x1;
    #pragma unroll
    for (int off = 32; off; off >>= 1) ss += __shfl_xor(ss, off);
    __shared__ float red[4];
    if ((t & 63) == 0) red[t >> 6] = ss;
    __syncthreads();
    float tot = red[0] + red[1] + red[2] + red[3];
    float scale = 1.0f / fmaxf(sqrtf(tot), 1e-8f);

    if (t < DP / 2) {                 // 160 bf16 pairs per row
        int e = t * 2;
        float a = (e < DN) ? row[e] * scale : 0.f;
        float b = (e + 1 < DN) ? row[e + 1] * scale : 0.f;
        __hip_bfloat162 p;
        p.x = __float2bfloat16(a);
        p.y = __float2bfloat16(b);
        tab2[(size_t)v * (DP / 2) + t] = p;
    }
}

// Slice buffers: [row][64 ushorts] = 128B rows; 16B chunks XOR-swizzled (R3-proven).
__device__ inline bf16x8 ldfrag(const ushort* buf, int row, int chunk) {
    int pos = chunk ^ (row & 7);
    return *(const bf16x8*)((const char*)buf + row * 128 + pos * 16);
}

// ---------------- kernel 2a: GEMM -> sim (f16) in global ----------------
__global__ __launch_bounds__(320, 4) void knrm_gemm(const int* __restrict__ cand,
                                                    const int* __restrict__ clik,
                                                    const ushort* __restrict__ tab,
                                                    _Float16* __restrict__ simg) {
    __shared__ __align__(16) ushort Abuf[160 * 64];   // 20 KB
    __shared__ __align__(16) ushort Bbuf[160 * 64];   // 20 KB
    __shared__ int tokA[160];
    __shared__ int tokB[160];

    const int t    = threadIdx.x;
    const int lane = t & 63;
    const int w    = t >> 6;          // wave 0..4 == candidate c
    const int bid  = blockIdx.x;
    const int b    = bid / 10;
    const int hc   = bid % 10;

    if (t < 160) tokA[t] = cand[b * (CN * LN) + t];
    else         tokB[t - 160] = clik[b * (HN * LN) + hc * 160 + (t - 160)];
    __syncthreads();

    const int m15 = lane & 15;
    const int g4  = lane >> 4;

    f32x4 acc[2][10];
    #pragma unroll
    for (int at = 0; at < 2; ++at)
        #pragma unroll
        for (int jg = 0; jg < 10; ++jg)
            acc[at][jg] = (f32x4){0.f, 0.f, 0.f, 0.f};

    for (int ss = 0; ss < 5; ++ss) {
        __syncthreads();
        {
            int4 rg[4];
            #pragma unroll
            for (int it = 0; it < 4; ++it) {
                int cid = it * 320 + t, row = cid >> 3, c = cid & 7;
                rg[it] = *(const int4*)((const char*)tab +
                    (size_t)tokA[row] * (DP * 2) + ss * 128 + ((c ^ (row & 7)) << 4));
            }
            #pragma unroll
            for (int it = 0; it < 4; ++it) {
                int cid = it * 320 + t, row = cid >> 3, c = cid & 7;
                *(int4*)((char*)Abuf + row * 128 + c * 16) = rg[it];
            }
            #pragma unroll
            for (int it = 0; it < 4; ++it) {
                int cid = it * 320 + t, row = cid >> 3, c = cid & 7;
                rg[it] = *(const int4*)((const char*)tab +
                    (size_t)tokB[row] * (DP * 2) + ss * 128 + ((c ^ (row & 7)) << 4));
            }
            #pragma unroll
            for (int it = 0; it < 4; ++it) {
                int cid = it * 320 + t, row = cid >> 3, c = cid & 7;
                *(int4*)((char*)Bbuf + row * 128 + c * 16) = rg[it];
            }
        }
        __syncthreads();
        #pragma unroll
        for (int kc = 0; kc < 2; ++kc) {
            bf16x8 af0 = ldfrag(Abuf, w * 32 + m15,      kc * 4 + g4);
            bf16x8 af1 = ldfrag(Abuf, w * 32 + 16 + m15, kc * 4 + g4);
            #pragma unroll
            for (int jg = 0; jg < 10; ++jg) {
                bf16x8 bf = ldfrag(Bbuf, jg * 16 + m15, kc * 4 + g4);
                acc[0][jg] = __builtin_amdgcn_mfma_f32_16x16x32_bf16(af0, bf, acc[0][jg], 0, 0, 0);
                acc[1][jg] = __builtin_amdgcn_mfma_f32_16x16x32_bf16(af1, bf, acc[1][jg], 0, 0, 0);
            }
        }
    }

    // store sim tiles: c = w, i = at*16 + g4*4 + r, h = hc*5 + hl, j = jgl*16 + m15
    // C/D layout col=lane&15, row=(lane>>4)*4+reg [m89-verified]
    #pragma unroll
    for (int hl = 0; hl < 5; ++hl)
        #pragma unroll
        for (int at = 0; at < 2; ++at)
            #pragma unroll
            for (int jgl = 0; jgl < 2; ++jgl)
                #pragma unroll
                for (int r = 0; r < 4; ++r) {
                    int i = at * 16 + g4 * 4 + r;
                    size_t idx = ((((size_t)(b * CN + w) * HN) + hc * 5 + hl) * LN + i) * LN
                                 + jgl * 16 + m15;
                    simg[idx] = (_Float16)acc[at][2 * hl + jgl][r];
                }
}

// ---------------- kernel 2b: pure streaming kernel-pooling ----------------
// thread = one (b,c,h,i) sim row; k unrolled with compile-time constants.
__global__ __launch_bounds__(256, 8) void knrm_pool(const _Float16* __restrict__ sim,
                                                    const float* __restrict__ ltr_w,
                                                    float* __restrict__ score) {
    const int n    = blockIdx.x * 256 + threadIdx.x;   // 1,024,000 threads
    const int lane = n & 63;
    const int wv   = n >> 6;          // ((b*C + c)*25 + h2)
    const int bc   = wv / 25;
    const int h2   = wv % 25;
    const int h    = h2 * 2 + (lane >> 5);
    const int i    = lane & 31;

    const _Float16* row = sim + ((size_t)(bc * HN + h) * LN + i) * LN;

    float P[KNN];
    #pragma unroll
    for (int k = 0; k < KNN; ++k) P[k] = 0.f;

    #pragma unroll 1
    for (int j = 0; j < LN; ++j) {
        float s = (float)row[j];
        #pragma unroll
        for (int k = 0; k < KNN; ++k) {
            const float sig = (k == KNN - 1) ? 0.001f : 0.1f;
            const float ak  = 1.1283791670955126f /*sqrt(log2e/(2*0.01))... folded*/ * 0.f +
                              __builtin_sqrtf(LOG2E / (2.0f * sig * sig));
            const float bk  = -(0.1f * (float)k - 0.9f) * ak;
            float d = fmaf(s, ak, bk);
            P[k] += FEXP2(-(d * d));
        }
    }

    const float* wrow = ltr_w + h * KNN;
    float res = 0.f;
    #pragma unroll
    for (int k = 0; k < KNN; ++k)
        res += wrow[k] * FLOG2(fmaxf(P[k], 1e-10f));
    res *= LN2F;

    #pragma unroll
    for (int off = 32; off; off >>= 1) res += __shfl_xor(res, off);
    if (lane == 0) atomicAdd(&score[bc], res);
}

// ---------------- fallback fused kernel (R3-proven) for small ws ----------------
__global__ __launch_bounds__(320, 4) void knrm_fused(const int* __restrict__ cand,
                                                     const int* __restrict__ clik,
                                                     const ushort* __restrict__ tab,
                                                     const float* __restrict__ ltr_w,
                                                     float* __restrict__ score) {
    __shared__ __align__(16) ushort   Abuf[160 * 64];
    __shared__ __align__(16) ushort   Bbuf[160 * 64];
    __shared__ __align__(16) _Float16 simbuf[160 * 32];
    __shared__ int   tokA[160];
    __shared__ int   tokB[160];
    __shared__ float red[5][5];

    const int t    = threadIdx.x;
    const int lane = t & 63;
    const int w    = t >> 6;
    const int bid  = blockIdx.x;
    const int b    = bid / 10;
    const int hc   = bid % 10;

    if (t < 160) tokA[t] = cand[b * (CN * LN) + t];
    else         tokB[t - 160] = clik[b * (HN * LN) + hc * 160 + (t - 160)];
    __syncthreads();

    const int m15 = lane & 15;
    const int g4  = lane >> 4;

    f32x4 acc[2][10];
    #pragma unroll
    for (int at = 0; at < 2; ++at)
        #pragma unroll
        for (int jg = 0; jg < 10; ++jg)
            acc[at][jg] = (f32x4){0.f, 0.f, 0.f, 0.f};

    for (int ss = 0; ss < 5; ++ss) {
        __syncthreads();
        {
            int4 rg[4];
            #pragma unroll
            for (int it = 0; it < 4; ++it) {
                int cid = it * 320 + t, row = cid >> 3, c = cid & 7;
                rg[it] = *(const int4*)((const char*)tab +
                    (size_t)tokA[row] * (DP * 2) + ss * 128 + ((c ^ (row & 7)) << 4));
            }
            #pragma unroll
            for (int it = 0; it < 4; ++it) {
                int cid = it * 320 + t, row = cid >> 3, c = cid & 7;
                *(int4*)((char*)Abuf + row * 128 + c * 16) = rg[it];
            }
            #pragma unroll
            for (int it = 0; it < 4; ++it) {
                int cid = it * 320 + t, row = cid >> 3, c = cid & 7;
                rg[it] = *(const int4*)((const char*)tab +
                    (size_t)tokB[row] * (DP * 2) + ss * 128 + ((c ^ (row & 7)) << 4));
            }
            #pragma unroll
            for (int it = 0; it < 4; ++it) {
                int cid = it * 320 + t, row = cid >> 3, c = cid & 7;
                *(int4*)((char*)Bbuf + row * 128 + c * 16) = rg[it];
            }
        }
        __syncthreads();
        #pragma unroll
        for (int kc = 0; kc < 2; ++kc) {
            bf16x8 af0 = ldfrag(Abuf, w * 32 + m15,      kc * 4 + g4);
            bf16x8 af1 = ldfrag(Abuf, w * 32 + 16 + m15, kc * 4 + g4);
            #pragma unroll
            for (int jg = 0; jg < 10; ++jg) {
                bf16x8 bf = ldfrag(Bbuf, jg * 16 + m15, kc * 4 + g4);
                acc[0][jg] = __builtin_amdgcn_mfma_f32_16x16x32_bf16(af0, bf, acc[0][jg], 0, 0, 0);
                acc[1][jg] = __builtin_amdgcn_mfma_f32_16x16x32_bf16(af1, bf, acc[1][jg], 0, 0, 0);
            }
        }
    }

    const int kq = t % 20;
    const int r0 = t / 20;
    const float sig = (kq == 19) ? 0.001f : 0.1f;
    const float ak  = sqrtf(LOG2E / (2.0f * sig * sig));
    const float bk  = -(0.1f * (float)kq - 0.9f) * ak;

    float accs[5] = {0.f, 0.f, 0.f, 0.f, 0.f};

    #pragma unroll
    for (int h = 0; h < 5; ++h) {
        __syncthreads();
        #pragma unroll
        for (int at = 0; at < 2; ++at)
            #pragma unroll
            for (int jgl = 0; jgl < 2; ++jgl)
                #pragma unroll
                for (int r = 0; r < 4; ++r) {
                    int i = w * 32 + at * 16 + g4 * 4 + r;
                    int j = jgl * 16 + m15;
                    simbuf[i * 32 + j] = (_Float16)acc[at][2 * h + jgl][r];
                }
        __syncthreads();

        const float wl = ltr_w[(hc * 5 + h) * KNN + kq] * LN2F;
        #pragma unroll
        for (int it = 0; it < 10; ++it) {
            const f16x8* srow = (const f16x8*)&simbuf[(it * 16 + r0) * 32];
            float p0 = 0.f, p1 = 0.f, p2 = 0.f, p3 = 0.f;
            #pragma unroll
            for (int jc = 0; jc < 4; ++jc) {
                f16x8 v = srow[jc];
                float d0 = fmaf((float)v[0], ak, bk);
                float d1 = fmaf((float)v[1], ak, bk);
                float d2 = fmaf((float)v[2], ak, bk);
                float d3 = fmaf((float)v[3], ak, bk);
                float d4 = fmaf((float)v[4], ak, bk);
                float d5 = fmaf((float)v[5], ak, bk);
                float d6 = fmaf((float)v[6], ak, bk);
                float d7 = fmaf((float)v[7], ak, bk);
                p0 += FEXP2(-(d0 * d0));
                p1 += FEXP2(-(d1 * d1));
                p2 += FEXP2(-(d2 * d2));
                p3 += FEXP2(-(d3 * d3));
                p0 += FEXP2(-(d4 * d4));
                p1 += FEXP2(-(d5 * d5));
                p2 += FEXP2(-(d6 * d6));
                p3 += FEXP2(-(d7 * d7));
            }
            float pooled = fmaxf((p0 + p1) + (p2 + p3), 1e-10f);
            accs[it >> 1] += FLOG2(pooled) * wl;
        }
    }

    #pragma unroll
    for (int c = 0; c < 5; ++c) {
        float v = accs[c];
        #pragma unroll
        for (int off = 32; off; off >>= 1) v += __shfl_xor(v, off);
        accs[c] = v;
    }
    __syncthreads();
    if (lane == 0)
        #pragma unroll
        for (int c = 0; c < 5; ++c) red[w][c] = accs[c];
    __syncthreads();
    if (t < 5) {
        float s = red[0][t] + red[1][t] + red[2][t] + red[3][t] + red[4][t];
        atomicAdd(&score[b * CN + t], s);
    }
}

// ---------------- kernel 3: log_softmax over C (ltr_b cancels) ----------------
__global__ __launch_bounds__(128) void knrm_final(const float* __restrict__ score,
                                                  float* __restrict__ out) {
    int b = threadIdx.x;
    if (b < BN) {
        float s[CN];
        float m = -1e30f;
        #pragma unroll
        for (int c = 0; c < CN; ++c) { s[c] = score[b * CN + c]; m = fmaxf(m, s[c]); }
        float sum = 0.f;
        #pragma unroll
        for (int c = 0; c < CN; ++c) sum += FEXP2((s[c] - m) * LOG2E);
        float lse = m + FLOG2(sum) * LN2F;
        #pragma unroll
        for (int c = 0; c < CN; ++c) out[b * CN + c] = s[c] - lse;
    }
}

extern "C" void kernel_launch(void* const* d_in, const int* in_sizes, int n_in,
                              void* d_out, int out_size, void* d_ws, size_t ws_size,
                              hipStream_t stream) {
    const int*   cand  = (const int*)d_in[0];   // [B,C,L]
    const int*   clik  = (const int*)d_in[1];   // [B,H,L]
    const float* emb   = (const float*)d_in[2]; // [VOCAB,D]
    const float* ltr_w = (const float*)d_in[3]; // [1,H*KN]
    float* out = (float*)d_out;

    const size_t TAB_B = (size_t)VOCABN * DP * 2;                 // 32,000,000
    const size_t SIM_B = (size_t)BN * CN * HN * LN * LN * 2;      // 65,536,000

    __hip_bfloat162* tab2 = (__hip_bfloat162*)d_ws;
    ushort* tab = (ushort*)d_ws;

    knorm_embed<<<VOCABN, 256, 0, stream>>>(emb, tab2);

    if (ws_size >= TAB_B + SIM_B + BN * CN * sizeof(float)) {
        _Float16* simg = (_Float16*)((char*)d_ws + TAB_B);
        float* score   = (float*)((char*)d_ws + TAB_B + SIM_B);
        hipMemsetAsync(score, 0, BN * CN * sizeof(float), stream);
        knrm_gemm<<<BN * 10, 320, 0, stream>>>(cand, clik, tab, simg);
        knrm_pool<<<(BN * CN * HN * LN) / 256, 256, 0, stream>>>(simg, ltr_w, score);
        knrm_final<<<1, 128, 0, stream>>>(score, out);
    } else {
        float* score = (float*)((char*)d_ws + TAB_B);
        hipMemsetAsync(score, 0, BN * CN * sizeof(float), stream);
        knrm_fused<<<BN * 10, 320, 0, stream>>>(cand, clik, tab, ltr_w, score);
        knrm_final<<<1, 128, 0, stream>>>(score, out);
    }
}